// Round 5
// baseline (244.510 us; speedup 1.0000x reference)
//
#include <hip/hip_runtime.h>

typedef unsigned long long u64;
typedef unsigned int u32;
typedef float f4n __attribute__((ext_vector_type(4)));   // native vec4 for NT stores

static constexpr int NF = 17;      // features per point
static constexpr int BCOL = 9;     // beta column
static constexpr int CCOL = 14;    // first ccoord column (17-3)
static constexpr int RPB = 512;    // rows per block in k_filter
static constexpr int CHUNK = 4096; // LDS NMS chunk capacity
static constexpr int REFCAP = 64;  // refs/event (packing bound for r=0.7 in unit cube is ~27)
static constexpr int SCAP = 32768; // survivor capacity per event
static constexpr int SUP_BPE = 32; // suppress blocks/event
static constexpr int SUP_CHK = 8;  // 32*256*8 = 65536 = P coverage

#define T_B_F ((float)0.2)         // matches numpy float32(0.2)
#define R2_F  ((float)(0.7*0.7))   // matches numpy promotion

__device__ __forceinline__ u64 shfl_down_u64(u64 v, int off){
    u32 lo = (u32)v, hi = (u32)(v >> 32);
    lo = __shfl_down(lo, off, 64);
    hi = __shfl_down(hi, off, 64);
    return ((u64)hi << 32) | lo;
}

// distance with NO fp contraction — must match numpy (mul,mul,mul,add,add)
__device__ __forceinline__ float dist2(float cx, float cy, float cz,
                                       float rx, float ry, float rz){
    #pragma clang fp contract(off)
    float dx = cx - rx, dy = cy - ry, dz = cz - rz;
    float sx = dx * dx, sy = dy * dy, sz = dz * dz;
    return (sx + sy) + sz;
}

__device__ __forceinline__ u64 makeKey(float beta, u32 idx){
    return ((u64)__float_as_uint(beta) << 32) | (u64)(0xFFFFFFFFu - idx);
}

// monotone bucket over beta in [0.2, 1.0) -> [0,255]
__device__ __forceinline__ int bucketOf(float b){
    int v = (int)((b - 0.2f) * 320.0f);
    return v > 255 ? 255 : v;
}

// ---------------- LDS NMS: greedy accept-argmax / suppress-ball --------------
// cbb[k] < 0 marks suppressed. Appends accepted refs to global refs arrays.
__device__ int lds_nms(float* cbx, float* cby, float* cbz, float* cbb, int* cbi,
                       int m, u64* rkey, int* rslot, u64* skey, int* sslot,
                       float4* refs_xyz, int* refs_idx, int refbase, int nref)
{
    int tid = threadIdx.x, lid = tid & 63, wid = tid >> 6;
    int nw = blockDim.x >> 6;
    for (int round = 0; round < REFCAP; round++){
        u64 bk = 0; int bs = -1;
        for (int k = tid; k < m; k += blockDim.x){
            float b = cbb[k];
            if (b >= 0.f){
                u64 kk = makeKey(b, (u32)cbi[k]);
                if (kk > bk){ bk = kk; bs = k; }
            }
        }
        #pragma unroll
        for (int off = 32; off > 0; off >>= 1){
            u64 ok = shfl_down_u64(bk, off);
            int os = __shfl_down(bs, off, 64);
            if (ok > bk){ bk = ok; bs = os; }
        }
        if (lid == 0){ rkey[wid] = bk; rslot[wid] = bs; }
        __syncthreads();
        if (tid == 0){
            u64 mb = 0; int ms = -1;
            for (int i = 0; i < nw; i++) if (rkey[i] > mb){ mb = rkey[i]; ms = rslot[i]; }
            *skey = mb; *sslot = ms;
        }
        __syncthreads();
        if (*skey == 0) break;
        int rs = *sslot;
        float rx = cbx[rs], ry = cby[rs], rz = cbz[rs];
        if (tid == 0 && nref < REFCAP){
            refs_xyz[refbase + nref] = make_float4(rx, ry, rz, 0.f);
            refs_idx[refbase + nref] = cbi[rs];
        }
        nref++;
        for (int k = tid; k < m; k += blockDim.x){
            if (cbb[k] >= 0.f && dist2(cbx[k], cby[k], cbz[k], rx, ry, rz) <= R2_F)
                cbb[k] = -1.f;
        }
        __syncthreads();
    }
    return nref;
}

// ---------------- kernel 0: zero control block + histograms ------------------
__global__ void k_init(u32* ws){
    for (int i = threadIdx.x; i < 4352; i += 1024) ws[i] = 0;  // 17408 B
}

// ---------------- kernel 1: pure-write NT zero of out ------------------------
__global__ __launch_bounds__(256) void k_zero(f4n* __restrict__ out4, int n4){
    int i = blockIdx.x * 256 + threadIdx.x;
    int stride = gridDim.x * 256;
    f4n z = {0.f, 0.f, 0.f, 0.f};
    for (; i < n4; i += stride) __builtin_nontemporal_store(z, &out4[i]);
}

// ---------------- kernel 2: filter beta>=T_B -> candidates + histogram -------
__global__ __launch_bounds__(256) void k_filter(
    const float4* __restrict__ x4,
    int* __restrict__ cnt, int* __restrict__ hist,
    float4* __restrict__ cand_xyz, int* __restrict__ cand_idx,
    int P, int chunksPerEvent)
{
    __shared__ float4 lrow[RPB];              // (cx,cy,cz,beta) per row — 8 KB
    __shared__ int lh[256];
    __shared__ int swc[4], swb[4], sbase;

    int e = blockIdx.x / chunksPerEvent;
    int chunk = blockIdx.x % chunksPerEvent;
    int rowStart = chunk * RPB;
    size_t tile4 = (size_t)blockIdx.x * (RPB * NF / 4);
    int tid = threadIdx.x;
    lh[tid] = 0;

    const int N4 = RPB * NF / 4;
    for (int i = tid; i < N4; i += 256){
        float4 v = x4[tile4 + i];
        float vv[4] = {v.x, v.y, v.z, v.w};
        int f0 = 4 * i;
        #pragma unroll
        for (int j = 0; j < 4; j++){
            int flat = f0 + j;
            int row = flat / NF;
            int col = flat - row * NF;
            if (col == BCOL)       ((float*)&lrow[row])[3] = vv[j];
            else if (col >= CCOL)  ((float*)&lrow[row])[col - CCOL] = vv[j];
        }
    }
    __syncthreads();

    int lid = tid & 63, wid = tid >> 6;
    float4 a0 = lrow[tid], a1 = lrow[tid + 256];
    bool k0 = (a0.w >= T_B_F), k1 = (a1.w >= T_B_F);
    u64 bal0 = __ballot(k0), bal1 = __ballot(k1);
    int wcnt = __popcll(bal0) + __popcll(bal1);
    if (k0) atomicAdd(&lh[bucketOf(a0.w)], 1);
    if (k1) atomicAdd(&lh[bucketOf(a1.w)], 1);
    if (lid == 0) swc[wid] = wcnt;
    __syncthreads();
    if (tid == 0){
        int tot = 0;
        for (int w = 0; w < 4; w++){ swb[w] = tot; tot += swc[w]; }
        sbase = tot ? atomicAdd(&cnt[e], tot) : 0;
    }
    __syncthreads();
    int base = sbase + swb[wid];
    u64 lm = (1ull << lid) - 1;
    size_t eoff = (size_t)e * P;
    if (k0){
        int pos = base + __popcll(bal0 & lm);
        cand_xyz[eoff + pos] = a0;
        cand_idx[eoff + pos] = rowStart + tid;
    }
    if (k1){
        int pos = base + __popcll(bal0) + __popcll(bal1 & lm);
        cand_xyz[eoff + pos] = a1;
        cand_idx[eoff + pos] = rowStart + tid + 256;
    }
    if (lh[tid]) atomicAdd(&hist[e * 256 + tid], lh[tid]);
}

// ---------------- kernel 3: cutoff + gather top chunk + LDS NMS --------------
__global__ __launch_bounds__(1024) void k_nms1(
    const int* __restrict__ hist, const float4* __restrict__ cand_xyz,
    const int* __restrict__ cand_idx, const int* __restrict__ cnt,
    float4* __restrict__ refs_xyz, int* __restrict__ refs_idx,
    int* __restrict__ nref1, int* __restrict__ cutoffB, int P)
{
    __shared__ float cbx[CHUNK], cby[CHUNK], cbz[CHUNK], cbb[CHUNK];
    __shared__ int cbi[CHUNK];
    __shared__ int lh[256];
    __shared__ int scut, sm;
    __shared__ u64 rkey[16]; __shared__ int rslot[16];
    __shared__ u64 skey; __shared__ int sslot;

    int e = blockIdx.x, tid = threadIdx.x;
    if (tid < 256) lh[tid] = hist[e * 256 + tid];
    if (tid == 0) sm = 0;
    __syncthreads();
    if (tid == 0){
        int tot = 0, c = 0;
        for (int b = 255; b >= 0; b--){
            if (tot + lh[b] > CHUNK){ c = b + 1; break; }
            tot += lh[b];
        }
        scut = c;
    }
    __syncthreads();
    int cut = scut, n = cnt[e];
    size_t eoff = (size_t)e * P;
    int lid = tid & 63;
    for (int i0 = 0; i0 < n; i0 += 1024){
        int i = i0 + tid;
        bool sel = false; float4 v = make_float4(0.f, 0.f, 0.f, 0.f);
        if (i < n){
            v = cand_xyz[eoff + i];
            sel = bucketOf(v.w) >= cut;
        }
        u64 bal = __ballot(sel);
        int cw = __popcll(bal);
        int base = 0;
        if (lid == 0) base = cw ? atomicAdd(&sm, cw) : 0;
        base = __shfl(base, 0, 64);
        if (sel){
            int pos = base + __popcll(bal & ((1ull << lid) - 1));
            cbx[pos] = v.x; cby[pos] = v.y; cbz[pos] = v.z; cbb[pos] = v.w;
            cbi[pos] = cand_idx[eoff + i];
        }
    }
    __syncthreads();
    int m = sm;
    int nref = lds_nms(cbx, cby, cbz, cbb, cbi, m, rkey, rslot, &skey, &sslot,
                       refs_xyz, refs_idx, e * REFCAP, 0);
    if (tid == 0){ nref1[e] = nref; cutoffB[e] = cut; }
}

// ---------------- kernel 4: filter below-cutoff candidates vs refs -----------
__global__ __launch_bounds__(256) void k_suppress(
    const float4* __restrict__ cand_xyz, const int* __restrict__ cand_idx,
    const int* __restrict__ cnt, const float4* __restrict__ refs_xyz,
    const int* __restrict__ nref1, const int* __restrict__ cutoffB,
    float4* __restrict__ surv_xyz, int* __restrict__ surv_idx,
    int* __restrict__ survcnt, int P)
{
    __shared__ float4 lref[REFCAP];
    __shared__ int swc[4], swb[4], sbase;
    int e = blockIdx.x / SUP_BPE, c = blockIdx.x % SUP_BPE;
    int nr = nref1[e], cut = cutoffB[e], n = cnt[e];
    for (int i = threadIdx.x; i < nr; i += 256) lref[i] = refs_xyz[e * REFCAP + i];
    __syncthreads();
    int tid = threadIdx.x, lid = tid & 63, wid = tid >> 6;
    size_t eoff = (size_t)e * P;
    int stride = SUP_BPE * 256;

    float4 cc[SUP_CHK]; int ix[SUP_CHK]; bool kp[SUP_CHK]; u64 bal[SUP_CHK];
    int wcnt = 0;
    #pragma unroll
    for (int k = 0; k < SUP_CHK; k++){
        int i = c * 256 + tid + k * stride;
        bool inb = i < n;
        int ii = inb ? i : 0;
        float4 v = cand_xyz[eoff + ii];
        bool keep = inb && (bucketOf(v.w) < cut);
        if (keep){
            for (int r = 0; r < nr; r++){
                float4 rf = lref[r];
                if (dist2(v.x, v.y, v.z, rf.x, rf.y, rf.z) <= R2_F){ keep = false; break; }
            }
        }
        cc[k] = v; kp[k] = keep;
        bal[k] = __ballot(keep);
        wcnt += __popcll(bal[k]);
        ix[k] = keep ? cand_idx[eoff + ii] : 0;
    }
    if (lid == 0) swc[wid] = wcnt;
    __syncthreads();
    if (tid == 0){
        int tot = 0;
        for (int w = 0; w < 4; w++){ swb[w] = tot; tot += swc[w]; }
        sbase = tot ? atomicAdd(&survcnt[e], tot) : 0;
    }
    __syncthreads();
    int pos = sbase + swb[wid];
    u64 lm = (1ull << lid) - 1;
    size_t soff = (size_t)e * SCAP;
    #pragma unroll
    for (int k = 0; k < SUP_CHK; k++){
        if (kp[k]){
            int p_ = pos + __popcll(bal[k] & lm);
            if (p_ < SCAP){ surv_xyz[soff + p_] = cc[k]; surv_idx[soff + p_] = ix[k]; }
        }
        pos += __popcll(bal[k]);
    }
}

// ---------------- kernel 5: NMS survivors + scatter + splits -----------------
__global__ __launch_bounds__(1024) void k_nms2(
    const float* __restrict__ x, float* __restrict__ out,
    const float4* __restrict__ surv_xyz, const int* __restrict__ surv_idx,
    const int* __restrict__ survcnt,
    float4* __restrict__ scr_xyz, int* __restrict__ scr_idx,   // dead cand arrays (fallback scratch)
    float4* __restrict__ refs_xyz, int* __restrict__ refs_idx,
    const int* __restrict__ nref1,
    int* __restrict__ ncond, int* __restrict__ done, int P, int E)
{
    __shared__ float cbx[CHUNK], cby[CHUNK], cbz[CHUNK], cbb[CHUNK];
    __shared__ int cbi[CHUNK];
    __shared__ u64 rkey[16]; __shared__ int rslot[16];
    __shared__ u64 skey; __shared__ int sslot;
    __shared__ int scnt2, sLast;

    int e = blockIdx.x, tid = threadIdx.x, lid = tid & 63, wid = tid >> 6;
    int m = survcnt[e]; if (m > SCAP) m = SCAP;
    size_t soff = (size_t)e * SCAP;
    int nref = nref1[e];

    const float4* sx = surv_xyz + soff;
    const int* si = surv_idx + soff;
    float4* fbx[2] = {scr_xyz + (size_t)e * P, scr_xyz + (size_t)e * P + SCAP};
    int* fbi[2] = {scr_idx + (size_t)e * P, scr_idx + (size_t)e * P + SCAP};
    int pp = 0;

    // fallback: shrink below CHUNK via single-accept global sweeps (unreached for bench data)
    while (m > CHUNK){
        u64 bk = 0; int bs = -1;
        for (int i = tid; i < m; i += 1024){
            float4 v = sx[i];
            u64 kk = makeKey(v.w, (u32)si[i]);
            if (kk > bk){ bk = kk; bs = i; }
        }
        #pragma unroll
        for (int off = 32; off > 0; off >>= 1){
            u64 ok = shfl_down_u64(bk, off);
            int os = __shfl_down(bs, off, 64);
            if (ok > bk){ bk = ok; bs = os; }
        }
        if (lid == 0){ rkey[wid] = bk; rslot[wid] = bs; }
        __syncthreads();
        if (tid == 0){
            u64 mb = 0; int ms = -1;
            for (int i = 0; i < 16; i++) if (rkey[i] > mb){ mb = rkey[i]; ms = rslot[i]; }
            sslot = ms; scnt2 = 0;
        }
        __syncthreads();
        float4 rv = sx[sslot];
        if (tid == 0 && nref < REFCAP){
            refs_xyz[e * REFCAP + nref] = make_float4(rv.x, rv.y, rv.z, 0.f);
            refs_idx[e * REFCAP + nref] = si[sslot];
        }
        nref++;
        __syncthreads();
        for (int i0 = 0; i0 < m; i0 += 1024){
            int i = i0 + tid;
            bool keep = false; float4 v = make_float4(0.f,0.f,0.f,0.f); int id_ = 0;
            if (i < m){
                v = sx[i]; id_ = si[i];
                keep = !(dist2(v.x, v.y, v.z, rv.x, rv.y, rv.z) <= R2_F);
            }
            u64 bal = __ballot(keep);
            int cw = __popcll(bal);
            int b_ = 0;
            if (lid == 0) b_ = cw ? atomicAdd(&scnt2, cw) : 0;
            b_ = __shfl(b_, 0, 64);
            if (keep){
                int p_ = b_ + __popcll(bal & ((1ull << lid) - 1));
                fbx[pp][p_] = v; fbi[pp][p_] = id_;
            }
        }
        __syncthreads();
        m = scnt2;
        sx = fbx[pp]; si = fbi[pp]; pp ^= 1;
        __syncthreads();
    }

    for (int i = tid; i < m; i += 1024){
        float4 v = sx[i];
        cbx[i] = v.x; cby[i] = v.y; cbz[i] = v.z; cbb[i] = v.w;
        cbi[i] = si[i];
    }
    __syncthreads();
    nref = lds_nms(cbx, cby, cbz, cbb, cbi, m, rkey, rslot, &skey, &sslot,
                   refs_xyz, refs_idx, e * REFCAP, nref);

    // scatter condensate rows (out already zeroed by k_zero)
    for (int i = tid; i < nref * NF; i += 1024){
        int j = i / NF, f = i - j * NF;
        int row = refs_idx[e * REFCAP + j];
        size_t b = ((size_t)e * P + row) * NF;
        out[b + f] = x[b + f];
    }
    if (tid == 0) atomicExch(&ncond[e], nref);
    __threadfence();
    __syncthreads();
    if (tid == 0) sLast = atomicAdd(done, 1);
    __syncthreads();
    if (sLast == E - 1 && tid == 0){
        size_t so = (size_t)E * P * NF;
        int s = 0;
        out[so] = 0.f;
        for (int i = 0; i < E; i++){
            s += atomicAdd(&ncond[i], 0);
            out[so + i + 1] = (float)s;
        }
    }
}

extern "C" void kernel_launch(void* const* d_in, const int* in_sizes, int n_in,
                              void* d_out, int out_size, void* d_ws, size_t ws_size,
                              hipStream_t stream) {
    const float* x = (const float*)d_in[0];
    int N = in_sizes[0] / NF;
    int E = in_sizes[1] - 1;
    int P = N / E;
    float* out = (float*)d_out;
    char* ws = (char*)d_ws;

    // ws layout (first 17408 B zeroed by k_init)
    int* cnt     = (int*)(ws + 0);        // [E]
    int* survcnt = (int*)(ws + 64);       // [E]
    int* ncond   = (int*)(ws + 128);      // [E]
    int* done    = (int*)(ws + 192);      // [1]
    int* nref1   = (int*)(ws + 256);      // [E]
    int* cutoffB = (int*)(ws + 320);      // [E]
    int* hist    = (int*)(ws + 1024);     // [E][256] = 16 KB
    float4* refs_xyz = (float4*)(ws + 20480);   // [E][REFCAP] = 16 KB
    int* refs_idx    = (int*)(ws + 36864);      // [E][REFCAP] = 4 KB
    size_t o = 65536;
    float4* cand_xyz = (float4*)(ws + o);                    // E*P*16 = 16 MB
    int* cand_idx    = (int*)(ws + o + (size_t)E*P*16);      // 4 MB
    float4* surv_xyz = (float4*)(ws + o + (size_t)E*P*20);   // E*SCAP*16 = 8 MB
    int* surv_idx    = (int*)(ws + o + (size_t)E*P*20 + (size_t)E*SCAP*16); // 2 MB

    k_init<<<1, 1024, 0, stream>>>((u32*)ws);

    int n4 = (N * NF) / 4;
    k_zero<<<2048, 256, 0, stream>>>((f4n*)out, n4);

    int chunksPerEvent = P / RPB;                   // 128
    k_filter<<<E * chunksPerEvent, 256, 0, stream>>>(
        (const float4*)x, cnt, hist, cand_xyz, cand_idx, P, chunksPerEvent);

    k_nms1<<<E, 1024, 0, stream>>>(
        hist, cand_xyz, cand_idx, cnt, refs_xyz, refs_idx, nref1, cutoffB, P);

    k_suppress<<<E * SUP_BPE, 256, 0, stream>>>(
        cand_xyz, cand_idx, cnt, refs_xyz, nref1, cutoffB,
        surv_xyz, surv_idx, survcnt, P);

    k_nms2<<<E, 1024, 0, stream>>>(
        x, out, surv_xyz, surv_idx, survcnt, cand_xyz, cand_idx,
        refs_xyz, refs_idx, nref1, ncond, done, P, E);
}

// Round 6
// 219.793 us; speedup vs baseline: 1.1125x; 1.1125x over previous
//
#include <hip/hip_runtime.h>

typedef unsigned long long u64;
typedef unsigned int u32;
typedef float f4n __attribute__((ext_vector_type(4)));   // native vec4 for NT stores

static constexpr int NF = 17;      // features per point
static constexpr int BCOL = 9;     // beta column
static constexpr int CCOL = 14;    // first ccoord column (17-3)
static constexpr int RPB = 512;    // rows per block in filter part
static constexpr int CHUNK = 4096; // LDS NMS chunk capacity
static constexpr int REFCAP = 64;  // refs/event (0.7-packing bound in unit cube ~27)
static constexpr int SCAP = 8192;  // survivor capacity per event
static constexpr int BPE = 32;     // wide-kernel blocks/event (gather & suppress)
static constexpr int WCHK = 8;     // 32*256*8 = 65536 = P coverage

#define T_B_F ((float)0.2)         // matches numpy float32(0.2)
#define R2_F  ((float)(0.7*0.7))   // matches numpy promotion

__device__ __forceinline__ u64 shfl_down_u64(u64 v, int off){
    u32 lo = (u32)v, hi = (u32)(v >> 32);
    lo = __shfl_down(lo, off, 64);
    hi = __shfl_down(hi, off, 64);
    return ((u64)hi << 32) | lo;
}

// distance with NO fp contraction — must match numpy (mul,mul,mul,add,add)
__device__ __forceinline__ float dist2(float cx, float cy, float cz,
                                       float rx, float ry, float rz){
    #pragma clang fp contract(off)
    float dx = cx - rx, dy = cy - ry, dz = cz - rz;
    float sx = dx * dx, sy = dy * dy, sz = dz * dz;
    return (sx + sy) + sz;
}

__device__ __forceinline__ u64 makeKey(float beta, u32 idx){
    return ((u64)__float_as_uint(beta) << 32) | (u64)(0xFFFFFFFFu - idx);
}

// monotone bucket over beta in [0.2, 1.0) -> [0,255]
__device__ __forceinline__ int bucketOf(float b){
    int v = (int)((b - 0.2f) * 320.0f);
    return v > 255 ? 255 : v;
}

// block-wide argmax with slot payload; blockDim must be 1024 (16 waves)
__device__ __forceinline__ void blockArgmax(u64 bk, int bs,
                                            u64* wkey, int* wslot,
                                            u64* skey, int* sslot){
    int tid = threadIdx.x, lid = tid & 63, wid = tid >> 6;
    #pragma unroll
    for (int off = 32; off > 0; off >>= 1){
        u64 ok = shfl_down_u64(bk, off);
        int os = __shfl_down(bs, off, 64);
        if (ok > bk){ bk = ok; bs = os; }
    }
    if (lid == 0){ wkey[wid] = bk; wslot[wid] = bs; }
    __syncthreads();
    if (wid == 0){
        u64 k2 = (lid < 16) ? wkey[lid] : 0;
        int s2 = (lid < 16) ? wslot[lid] : -1;
        #pragma unroll
        for (int off = 8; off > 0; off >>= 1){
            u64 ok = shfl_down_u64(k2, off);
            int os = __shfl_down(s2, off, 64);
            if (ok > k2){ k2 = ok; s2 = os; }
        }
        if (lid == 0){ *skey = k2; *sslot = s2; }
    }
    __syncthreads();
}

// fast LDS NMS: fused suppress+argmax pass, 2 barriers/round
__device__ int lds_nms_fast(float4* cp, float* cb, int* ci, int m,
                            u64* wkey, int* wslot, u64* skey, int* sslot,
                            float4* refs_xyz, int* refs_idx, int refbase, int nref)
{
    int tid = threadIdx.x;
    u64 bk = 0; int bs = -1;
    for (int k = tid; k < m; k += 1024){
        u64 kk = makeKey(cb[k], (u32)ci[k]);
        if (kk > bk){ bk = kk; bs = k; }
    }
    blockArgmax(bk, bs, wkey, wslot, skey, sslot);
    while (*skey != 0){
        int rs = *sslot;
        float4 rv = cp[rs];
        if (tid == 0 && nref < REFCAP){
            refs_xyz[refbase + nref] = rv;
            refs_idx[refbase + nref] = ci[rs];
        }
        nref++;
        bk = 0; bs = -1;
        for (int k = tid; k < m; k += 1024){
            float b = cb[k];
            if (b >= 0.f){
                float4 p = cp[k];
                if (dist2(p.x, p.y, p.z, rv.x, rv.y, rv.z) <= R2_F) cb[k] = -1.f;
                else { u64 kk = makeKey(b, (u32)ci[k]); if (kk > bk){ bk = kk; bs = k; } }
            }
        }
        blockArgmax(bk, bs, wkey, wslot, skey, sslot);
    }
    return nref;
}

// ---------------- kernel 0: zero control block + histograms ------------------
__global__ void k_init(u32* ws){
    for (int i = threadIdx.x; i < 4352; i += 1024) ws[i] = 0;  // 17408 B
}

// ---------------- kernel 1: fused NT-zero of out + filter/histogram ----------
__global__ __launch_bounds__(256) void k_main(
    const float4* __restrict__ x4, f4n* __restrict__ out4, int n4out,
    int* __restrict__ cnt, int* __restrict__ hist,
    float4* __restrict__ cand_xyz, int* __restrict__ cand_idx,
    int P, int chunksPerEvent, int filterBlocks)
{
    __shared__ float4 lrow[RPB];              // (cx,cy,cz,beta) per row — 8 KB
    __shared__ int lh[256];
    __shared__ int swc[4], swb[4], sbase;

    int b = blockIdx.x;
    if (b >= filterBlocks){                   // -------- zero part --------
        int i = (b - filterBlocks) * 256 + threadIdx.x;
        int stride = (gridDim.x - filterBlocks) * 256;
        f4n z = {0.f, 0.f, 0.f, 0.f};
        for (; i < n4out; i += stride) __builtin_nontemporal_store(z, &out4[i]);
        return;
    }
    // -------- filter part --------
    int e = b / chunksPerEvent;
    int chunk = b % chunksPerEvent;
    int rowStart = chunk * RPB;
    size_t tile4 = (size_t)b * (RPB * NF / 4);
    int tid = threadIdx.x;
    lh[tid] = 0;

    const int N4 = RPB * NF / 4;
    for (int i = tid; i < N4; i += 256){
        float4 v = x4[tile4 + i];
        float vv[4] = {v.x, v.y, v.z, v.w};
        int f0 = 4 * i;
        #pragma unroll
        for (int j = 0; j < 4; j++){
            int flat = f0 + j;
            int row = flat / NF;
            int col = flat - row * NF;
            if (col == BCOL)       ((float*)&lrow[row])[3] = vv[j];
            else if (col >= CCOL)  ((float*)&lrow[row])[col - CCOL] = vv[j];
        }
    }
    __syncthreads();

    int lid = tid & 63, wid = tid >> 6;
    float4 a0 = lrow[tid], a1 = lrow[tid + 256];
    bool k0 = (a0.w >= T_B_F), k1 = (a1.w >= T_B_F);
    u64 bal0 = __ballot(k0), bal1 = __ballot(k1);
    int wcnt = __popcll(bal0) + __popcll(bal1);
    if (k0) atomicAdd(&lh[bucketOf(a0.w)], 1);
    if (k1) atomicAdd(&lh[bucketOf(a1.w)], 1);
    if (lid == 0) swc[wid] = wcnt;
    __syncthreads();
    if (tid == 0){
        int tot = 0;
        for (int w = 0; w < 4; w++){ swb[w] = tot; tot += swc[w]; }
        sbase = tot ? atomicAdd(&cnt[e], tot) : 0;
    }
    __syncthreads();
    int base = sbase + swb[wid];
    u64 lm = (1ull << lid) - 1;
    size_t eoff = (size_t)e * P;
    if (k0){
        int pos = base + __popcll(bal0 & lm);
        cand_xyz[eoff + pos] = a0;
        cand_idx[eoff + pos] = rowStart + tid;
    }
    if (k1){
        int pos = base + __popcll(bal0) + __popcll(bal1 & lm);
        cand_xyz[eoff + pos] = a1;
        cand_idx[eoff + pos] = rowStart + tid + 256;
    }
    if (lh[tid]) atomicAdd(&hist[e * 256 + tid], lh[tid]);
}

// ---------------- kernel 2: wide gather of top-cutoff candidates -------------
__global__ __launch_bounds__(256) void k_gather(
    const int* __restrict__ hist, const float4* __restrict__ cand_xyz,
    const int* __restrict__ cand_idx, const int* __restrict__ cnt,
    float4* __restrict__ top_xyz, int* __restrict__ top_idx,
    int* __restrict__ topcnt, int* __restrict__ cutoffB, int P)
{
    __shared__ int lh[256];
    __shared__ int swc[4], swb[4], sbase, scut;
    int e = blockIdx.x / BPE, c = blockIdx.x % BPE;
    int tid = threadIdx.x;
    lh[tid] = hist[e * 256 + tid];
    __syncthreads();
    if (tid == 0){
        int tot = 0, cu = 0;
        for (int bb = 255; bb >= 0; bb--){
            if (tot + lh[bb] > CHUNK){ cu = bb + 1; break; }
            tot += lh[bb];
        }
        scut = cu;
        if (c == 0) cutoffB[e] = cu;
    }
    __syncthreads();
    int cut = scut, n = cnt[e];
    int lid = tid & 63, wid = tid >> 6;
    size_t eoff = (size_t)e * P;
    int stride = BPE * 256;

    float4 cc[WCHK]; int ix[WCHK]; bool kp[WCHK]; u64 bal[WCHK];
    int wcnt = 0;
    #pragma unroll
    for (int k = 0; k < WCHK; k++){
        int i = c * 256 + tid + k * stride;
        bool inb = i < n;
        int ii = inb ? i : 0;
        float4 v = cand_xyz[eoff + ii];
        kp[k] = inb && (bucketOf(v.w) >= cut);
        cc[k] = v;
        bal[k] = __ballot(kp[k]);
        wcnt += __popcll(bal[k]);
        ix[k] = kp[k] ? cand_idx[eoff + ii] : 0;
    }
    if (lid == 0) swc[wid] = wcnt;
    __syncthreads();
    if (tid == 0){
        int tot = 0;
        for (int w = 0; w < 4; w++){ swb[w] = tot; tot += swc[w]; }
        sbase = tot ? atomicAdd(&topcnt[e], tot) : 0;
    }
    __syncthreads();
    int pos = sbase + swb[wid];
    u64 lm = (1ull << lid) - 1;
    #pragma unroll
    for (int k = 0; k < WCHK; k++){
        if (kp[k]){
            int p_ = pos + __popcll(bal[k] & lm);
            top_xyz[e * CHUNK + p_] = cc[k];
            top_idx[e * CHUNK + p_] = ix[k];
        }
        pos += __popcll(bal[k]);
    }
}

// ---------------- kernel 3: LDS NMS of top chunk -----------------------------
__global__ __launch_bounds__(1024) void k_nms1(
    const float4* __restrict__ top_xyz, const int* __restrict__ top_idx,
    const int* __restrict__ topcnt,
    float4* __restrict__ refs_xyz, int* __restrict__ refs_idx,
    int* __restrict__ nref1)
{
    __shared__ float4 cp[CHUNK];   // 64 KB
    __shared__ float cb[CHUNK];    // 16 KB
    __shared__ int ci[CHUNK];      // 16 KB
    __shared__ u64 wkey[16]; __shared__ int wslot[16];
    __shared__ u64 skey; __shared__ int sslot;

    int e = blockIdx.x, tid = threadIdx.x;
    int m = topcnt[e]; if (m > CHUNK) m = CHUNK;
    for (int i = tid; i < m; i += 1024){
        float4 v = top_xyz[e * CHUNK + i];
        cp[i] = v; cb[i] = v.w; ci[i] = top_idx[e * CHUNK + i];
    }
    __syncthreads();
    int nref = lds_nms_fast(cp, cb, ci, m, wkey, wslot, &skey, &sslot,
                            refs_xyz, refs_idx, e * REFCAP, 0);
    if (tid == 0) nref1[e] = nref;
}

// ---------------- kernel 4: filter below-cutoff candidates vs refs -----------
__global__ __launch_bounds__(256) void k_suppress(
    const float4* __restrict__ cand_xyz, const int* __restrict__ cand_idx,
    const int* __restrict__ cnt, const float4* __restrict__ refs_xyz,
    const int* __restrict__ nref1, const int* __restrict__ cutoffB,
    float4* __restrict__ surv_xyz, int* __restrict__ surv_idx,
    int* __restrict__ survcnt, int P)
{
    __shared__ float4 lref[REFCAP];
    __shared__ int swc[4], swb[4], sbase;
    int e = blockIdx.x / BPE, c = blockIdx.x % BPE;
    int nr = nref1[e]; if (nr > REFCAP) nr = REFCAP;
    int cut = cutoffB[e], n = cnt[e];
    for (int i = threadIdx.x; i < nr; i += 256) lref[i] = refs_xyz[e * REFCAP + i];
    __syncthreads();
    int tid = threadIdx.x, lid = tid & 63, wid = tid >> 6;
    size_t eoff = (size_t)e * P;
    int stride = BPE * 256;

    float4 cc[WCHK]; int ix[WCHK]; bool kp[WCHK]; u64 bal[WCHK];
    int wcnt = 0;
    #pragma unroll
    for (int k = 0; k < WCHK; k++){
        int i = c * 256 + tid + k * stride;
        bool inb = i < n;
        int ii = inb ? i : 0;
        float4 v = cand_xyz[eoff + ii];
        bool keep = inb && (bucketOf(v.w) < cut);
        if (keep){
            for (int r = 0; r < nr; r++){
                float4 rf = lref[r];
                if (dist2(v.x, v.y, v.z, rf.x, rf.y, rf.z) <= R2_F){ keep = false; break; }
            }
        }
        cc[k] = v; kp[k] = keep;
        bal[k] = __ballot(keep);
        wcnt += __popcll(bal[k]);
        ix[k] = keep ? cand_idx[eoff + ii] : 0;
    }
    if (lid == 0) swc[wid] = wcnt;
    __syncthreads();
    if (tid == 0){
        int tot = 0;
        for (int w = 0; w < 4; w++){ swb[w] = tot; tot += swc[w]; }
        sbase = tot ? atomicAdd(&survcnt[e], tot) : 0;
    }
    __syncthreads();
    int pos = sbase + swb[wid];
    u64 lm = (1ull << lid) - 1;
    size_t soff = (size_t)e * SCAP;
    #pragma unroll
    for (int k = 0; k < WCHK; k++){
        if (kp[k]){
            int p_ = pos + __popcll(bal[k] & lm);
            if (p_ < SCAP){ surv_xyz[soff + p_] = cc[k]; surv_idx[soff + p_] = ix[k]; }
        }
        pos += __popcll(bal[k]);
    }
}

// ---------------- kernel 5: NMS survivors + scatter + splits -----------------
__global__ __launch_bounds__(1024) void k_nms2(
    const float* __restrict__ x, float* __restrict__ out,
    const float4* __restrict__ surv_xyz, const int* __restrict__ surv_idx,
    const int* __restrict__ survcnt,
    float4* __restrict__ scr_xyz, int* __restrict__ scr_idx,   // dead cand arrays
    float4* __restrict__ refs_xyz, int* __restrict__ refs_idx,
    const int* __restrict__ nref1,
    int* __restrict__ ncond, int* __restrict__ done, int P, int E)
{
    __shared__ float4 cp[CHUNK];
    __shared__ float cb[CHUNK];
    __shared__ int ci[CHUNK];
    __shared__ u64 wkey[16]; __shared__ int wslot[16];
    __shared__ u64 skey; __shared__ int sslot;
    __shared__ int scnt2, sLast;

    int e = blockIdx.x, tid = threadIdx.x, lid = tid & 63, wid = tid >> 6;
    int m = survcnt[e]; if (m > SCAP) m = SCAP;
    size_t soff = (size_t)e * SCAP;
    int nref = nref1[e]; if (nref > REFCAP) nref = REFCAP;

    const float4* sx = surv_xyz + soff;
    const int* si = surv_idx + soff;
    float4* fbx[2] = {scr_xyz + (size_t)e * P, scr_xyz + (size_t)e * P + SCAP};
    int* fbi[2] = {scr_idx + (size_t)e * P, scr_idx + (size_t)e * P + SCAP};
    int pp = 0;

    // fallback: shrink below CHUNK via single-accept global sweeps (unreached for bench data)
    while (m > CHUNK){
        u64 bk = 0; int bs = -1;
        for (int i = tid; i < m; i += 1024){
            float4 v = sx[i];
            u64 kk = makeKey(v.w, (u32)si[i]);
            if (kk > bk){ bk = kk; bs = i; }
        }
        blockArgmax(bk, bs, wkey, wslot, &skey, &sslot);
        if (tid == 0) scnt2 = 0;
        __syncthreads();
        float4 rv = sx[sslot];
        if (tid == 0 && nref < REFCAP){
            refs_xyz[e * REFCAP + nref] = rv;
            refs_idx[e * REFCAP + nref] = si[sslot];
        }
        nref++;
        __syncthreads();
        for (int i0 = 0; i0 < m; i0 += 1024){
            int i = i0 + tid;
            bool keep = false; float4 v = make_float4(0.f,0.f,0.f,0.f); int id_ = 0;
            if (i < m){
                v = sx[i]; id_ = si[i];
                keep = !(dist2(v.x, v.y, v.z, rv.x, rv.y, rv.z) <= R2_F);
            }
            u64 bal = __ballot(keep);
            int cw = __popcll(bal);
            int b_ = 0;
            if (lid == 0) b_ = cw ? atomicAdd(&scnt2, cw) : 0;
            b_ = __shfl(b_, 0, 64);
            if (keep){
                int p_ = b_ + __popcll(bal & ((1ull << lid) - 1));
                fbx[pp][p_] = v; fbi[pp][p_] = id_;
            }
        }
        __syncthreads();
        m = scnt2;
        sx = fbx[pp]; si = fbi[pp]; pp ^= 1;
        __syncthreads();
    }

    for (int i = tid; i < m; i += 1024){
        float4 v = sx[i];
        cp[i] = v; cb[i] = v.w; ci[i] = si[i];
    }
    __syncthreads();
    nref = lds_nms_fast(cp, cb, ci, m, wkey, wslot, &skey, &sslot,
                        refs_xyz, refs_idx, e * REFCAP, nref);
    if (nref > REFCAP) nref = REFCAP;

    // scatter condensate rows (out already zeroed by k_main)
    for (int i = tid; i < nref * NF; i += 1024){
        int j = i / NF, f = i - j * NF;
        int row = refs_idx[e * REFCAP + j];
        size_t b = ((size_t)e * P + row) * NF;
        out[b + f] = x[b + f];
    }
    if (tid == 0) atomicExch(&ncond[e], nref);
    __threadfence();
    __syncthreads();
    if (tid == 0) sLast = atomicAdd(done, 1);
    __syncthreads();
    if (sLast == E - 1 && tid == 0){
        size_t so = (size_t)E * P * NF;
        int s = 0;
        out[so] = 0.f;
        for (int i = 0; i < E; i++){
            s += atomicAdd(&ncond[i], 0);
            out[so + i + 1] = (float)s;
        }
    }
}

extern "C" void kernel_launch(void* const* d_in, const int* in_sizes, int n_in,
                              void* d_out, int out_size, void* d_ws, size_t ws_size,
                              hipStream_t stream) {
    const float* x = (const float*)d_in[0];
    int N = in_sizes[0] / NF;
    int E = in_sizes[1] - 1;
    int P = N / E;
    float* out = (float*)d_out;
    char* ws = (char*)d_ws;

    // ws layout (first 17408 B zeroed by k_init)
    int* cnt     = (int*)(ws + 0);        // [E]
    int* survcnt = (int*)(ws + 64);       // [E]
    int* ncond   = (int*)(ws + 128);      // [E]
    int* done    = (int*)(ws + 192);      // [1]
    int* nref1   = (int*)(ws + 256);      // [E]
    int* cutoffB = (int*)(ws + 320);      // [E]
    int* topcnt  = (int*)(ws + 384);      // [E]
    int* hist    = (int*)(ws + 1024);     // [E][256] = 16 KB
    float4* refs_xyz = (float4*)(ws + 20480);   // [E][REFCAP] = 16 KB
    int* refs_idx    = (int*)(ws + 36864);      // [E][REFCAP] = 4 KB
    float4* top_xyz  = (float4*)(ws + 65536);               // E*CHUNK*16 = 1 MB
    int* top_idx     = (int*)(ws + 65536 + (size_t)E*CHUNK*16);   // 256 KB
    size_t o = 65536 + (size_t)E*CHUNK*20;
    float4* cand_xyz = (float4*)(ws + o);                    // E*P*16 = 16 MB
    int* cand_idx    = (int*)(ws + o + (size_t)E*P*16);      // 4 MB
    float4* surv_xyz = (float4*)(ws + o + (size_t)E*P*20);   // E*SCAP*16 = 2 MB
    int* surv_idx    = (int*)(ws + o + (size_t)E*P*20 + (size_t)E*SCAP*16); // 512 KB

    k_init<<<1, 1024, 0, stream>>>((u32*)ws);

    int chunksPerEvent = P / RPB;                   // 128
    int filterBlocks = E * chunksPerEvent;          // 2048
    int zeroBlocks = 1024;
    int n4out = (N * NF) / 4;
    k_main<<<filterBlocks + zeroBlocks, 256, 0, stream>>>(
        (const float4*)x, (f4n*)out, n4out, cnt, hist, cand_xyz, cand_idx,
        P, chunksPerEvent, filterBlocks);

    k_gather<<<E * BPE, 256, 0, stream>>>(
        hist, cand_xyz, cand_idx, cnt, top_xyz, top_idx, topcnt, cutoffB, P);

    k_nms1<<<E, 1024, 0, stream>>>(
        top_xyz, top_idx, topcnt, refs_xyz, refs_idx, nref1);

    k_suppress<<<E * BPE, 256, 0, stream>>>(
        cand_xyz, cand_idx, cnt, refs_xyz, nref1, cutoffB,
        surv_xyz, surv_idx, survcnt, P);

    k_nms2<<<E, 1024, 0, stream>>>(
        x, out, surv_xyz, surv_idx, survcnt, cand_xyz, cand_idx,
        refs_xyz, refs_idx, nref1, ncond, done, P, E);
}